// Round 1
// baseline (668.585 us; speedup 1.0000x reference)
//
#include <hip/hip_runtime.h>
#include <hip/hip_bf16.h>

#define T_SEQ 512

typedef __attribute__((ext_vector_type(8))) short frag_ab;
typedef __attribute__((ext_vector_type(4))) float frag_cd;
typedef __attribute__((ext_vector_type(4))) float f4;

static __device__ __forceinline__ unsigned short f2bf(float f){
    union { float f; unsigned u; } v; v.f = f;
    unsigned r = v.u + 0x7fffu + ((v.u >> 16) & 1u);
    return (unsigned short)(r >> 16);
}
static __device__ __forceinline__ float bf2f(unsigned short h){
    union { unsigned u; float f; } v; v.u = ((unsigned)h) << 16;
    return v.f;
}
static __device__ __forceinline__ float sigf(float v){
    float e = __expf(-fabsf(v));
    float p = __builtin_amdgcn_rcpf(1.0f + e);
    return v >= 0.0f ? p : 1.0f - p;
}
static __device__ __forceinline__ float tanhf2(float v){
    float e = __expf(-2.0f * fabsf(v));
    float t = (1.0f - e) * __builtin_amdgcn_rcpf(1.0f + e);
    return v >= 0.0f ? t : -t;
}
static __device__ __forceinline__ frag_ab loadBfrag(const float* __restrict__ W, int ldk, int jcol, int k0){
    const float* p = W + jcol * ldk + k0;
    frag_ab r;
    #pragma unroll
    for (int i = 0; i < 8; ++i) r[i] = (short)f2bf(p[i]);
    return r;
}

#define MFMA(a,b,c) __builtin_amdgcn_mfma_f32_16x16x32_bf16((a),(b),(c),0,0,0)

__global__ __launch_bounds__(256, 1)
void gru_fused(const float* __restrict__ x,
               const float* __restrict__ Wih1, const float* __restrict__ Whh1,
               const float* __restrict__ bih1, const float* __restrict__ bhh1,
               const float* __restrict__ Wih2, const float* __restrict__ Whh2,
               const float* __restrict__ bih2, const float* __restrict__ bhh2,
               const float* __restrict__ Wfc,  const float* __restrict__ bfc,
               const float* __restrict__ Wout, const float* __restrict__ bout,
               float* __restrict__ out)
{
    __shared__ __align__(16) unsigned short H1hi[16*72], H1lo[16*72];
    __shared__ __align__(16) unsigned short H2hi[16*40], H2lo[16*40];
    __shared__ __align__(16) float C2ih[16*100], C2hh[16*100];

    const int tid  = threadIdx.x;
    const int wv   = tid >> 6;       // wave 0..3
    const int lane = tid & 63;
    const int lrow = lane & 15;      // A-frag row / C-frag col
    const int lq   = lane >> 4;      // k-group / C-row group
    const int j2t  = tid & 31;

    for (int i = tid; i < 16*72; i += 256){ H1hi[i] = 0; H1lo[i] = 0; }
    for (int i = tid; i < 16*40; i += 256){ H2hi[i] = 0; H2lo[i] = 0; }

    // biases (register-resident, matched to owned output columns)
    const int j1 = wv*16 + lrow;
    const float bi1r = bih1[j1], bi1z = bih1[64+j1], bi1n = bih1[128+j1];
    const float bh1r = bhh1[j1], bh1z = bhh1[64+j1], bh1n = bhh1[128+j1];
    const float bi2r = bih2[j2t], bi2z = bih2[32+j2t], bi2n = bih2[64+j2t];
    const float bh2r = bhh2[j2t], bh2z = bhh2[32+j2t], bh2n = bhh2[64+j2t];

    // weight B-fragments in registers (bf16 hi). Row-interleaved: wave wv's
    // fragment g covers weight rows g*64 + wv*16 + col -> gate math gets
    // matched (r,z,n) for unit j = wv*16+col locally.
    frag_ab Bih1[3][2], Bhh1[3][2];
    #pragma unroll
    for (int g = 0; g < 3; ++g){
        #pragma unroll
        for (int kf = 0; kf < 2; ++kf){
            const int j  = g*64 + wv*16 + lrow;
            const int k0 = kf*32 + 8*lq;
            Bih1[g][kf] = loadBfrag(Wih1, 64, j, k0);
            Bhh1[g][kf] = loadBfrag(Whh1, 64, j, k0);
        }
    }
    frag_ab Bih2[3][2];
    frag_ab Bhh2[3];
    if (wv < 2){
        #pragma unroll
        for (int nf = 0; nf < 3; ++nf)
            #pragma unroll
            for (int kf = 0; kf < 2; ++kf)
                Bih2[nf][kf] = loadBfrag(Wih2, 64, wv*48 + nf*16 + lrow, kf*32 + 8*lq);
    } else {
        #pragma unroll
        for (int nf = 0; nf < 3; ++nf)
            Bhh2[nf] = loadBfrag(Whh2, 32, (wv-2)*48 + nf*16 + lrow, 8*lq);
    }

    __syncthreads();

    // x A-fragments straight from global; rows 8..15 clone rows 0..7 (L1 hits)
    const float* xrow = x + (size_t)(blockIdx.x*8 + (lrow & 7)) * T_SEQ * 64;
    f4 xc[2][2], xn[2][2];
    #pragma unroll
    for (int kf = 0; kf < 2; ++kf)
        #pragma unroll
        for (int h = 0; h < 2; ++h)
            xc[kf][h] = *(const f4*)(xrow + kf*32 + 8*lq + 4*h);

    float hp[4] = {0.f, 0.f, 0.f, 0.f};   // h1 rows lq*4+r at col wv*16+lrow
    float h2r = 0.f;                       // h2 unit (tid>>5, tid&31)

    for (int t = 0; t < T_SEQ; ++t){
        const int t1 = (t+1 < T_SEQ) ? t+1 : T_SEQ-1;
        #pragma unroll
        for (int kf = 0; kf < 2; ++kf)
            #pragma unroll
            for (int h = 0; h < 2; ++h)
                xn[kf][h] = *(const f4*)(xrow + (size_t)t1*64 + kf*32 + 8*lq + 4*h);

        // split x into hi/lo bf16 fragments
        frag_ab xhi[2], xlo[2];
        #pragma unroll
        for (int kf = 0; kf < 2; ++kf){
            #pragma unroll
            for (int i = 0; i < 8; ++i){
                const float f = (i < 4) ? xc[kf][0][i] : xc[kf][1][i-4];
                const unsigned short hb = f2bf(f);
                xhi[kf][i] = (short)hb;
                xlo[kf][i] = (short)f2bf(f - bf2f(hb));
            }
        }
        frag_ab h1h[2], h1l[2];
        #pragma unroll
        for (int kf = 0; kf < 2; ++kf){
            const int k0 = kf*32 + 8*lq;
            h1h[kf] = *(const frag_ab*)(H1hi + lrow*72 + k0);
            h1l[kf] = *(const frag_ab*)(H1lo + lrow*72 + k0);
        }

        frag_cd aih[3], ahh[3];
        #pragma unroll
        for (int g = 0; g < 3; ++g){
            frag_cd z0 = {0.f,0.f,0.f,0.f};
            aih[g] = z0; ahh[g] = z0;
        }
        #pragma unroll
        for (int g = 0; g < 3; ++g){
            #pragma unroll
            for (int kf = 0; kf < 2; ++kf){
                aih[g] = MFMA(xhi[kf], Bih1[g][kf], aih[g]);
                aih[g] = MFMA(xlo[kf], Bih1[g][kf], aih[g]);
                ahh[g] = MFMA(h1h[kf], Bhh1[g][kf], ahh[g]);
                ahh[g] = MFMA(h1l[kf], Bhh1[g][kf], ahh[g]);
            }
        }
        __syncthreads();   // all waves done reading H1(t-1)

        // layer-1 gates; fp32 state in regs; publish h1 hi/lo to LDS
        #pragma unroll
        for (int r = 0; r < 4; ++r){
            const float xr = aih[0][r] + bi1r, hr = ahh[0][r] + bh1r;
            const float xz = aih[1][r] + bi1z, hz = ahh[1][r] + bh1z;
            const float xg = aih[2][r] + bi1n, hn = ahh[2][r] + bh1n;
            const float rg = sigf(xr + hr);
            const float zg = sigf(xz + hz);
            const float ng = tanhf2(xg + rg*hn);
            const float hnew = (1.f - zg)*ng + zg*hp[r];
            hp[r] = hnew;
            const int row = lq*4 + r, col = wv*16 + lrow;
            const unsigned short hb = f2bf(hnew);
            H1hi[row*72 + col] = hb;
            H1lo[row*72 + col] = f2bf(hnew - bf2f(hb));
        }
        __syncthreads();   // H1(t) visible

        if (wv < 2){       // ih2 = h1(t) @ Wih2^T
            frag_ab nh[2], nl[2];
            #pragma unroll
            for (int kf = 0; kf < 2; ++kf){
                const int k0 = kf*32 + 8*lq;
                nh[kf] = *(const frag_ab*)(H1hi + lrow*72 + k0);
                nl[kf] = *(const frag_ab*)(H1lo + lrow*72 + k0);
            }
            #pragma unroll
            for (int nf = 0; nf < 3; ++nf){
                frag_cd a2 = {0.f,0.f,0.f,0.f};
                #pragma unroll
                for (int kf = 0; kf < 2; ++kf){
                    a2 = MFMA(nh[kf], Bih2[nf][kf], a2);
                    a2 = MFMA(nl[kf], Bih2[nf][kf], a2);
                }
                #pragma unroll
                for (int r = 0; r < 4; ++r)
                    C2ih[(lq*4+r)*100 + wv*48 + nf*16 + lrow] = a2[r];
            }
        } else {           // hh2 = h2(t-1) @ Whh2^T (K=32)
            frag_ab g2h = *(const frag_ab*)(H2hi + lrow*40 + 8*lq);
            frag_ab g2l = *(const frag_ab*)(H2lo + lrow*40 + 8*lq);
            #pragma unroll
            for (int nf = 0; nf < 3; ++nf){
                frag_cd a2 = {0.f,0.f,0.f,0.f};
                a2 = MFMA(g2h, Bhh2[nf], a2);
                a2 = MFMA(g2l, Bhh2[nf], a2);
                #pragma unroll
                for (int r = 0; r < 4; ++r)
                    C2hh[(lq*4+r)*100 + (wv-2)*48 + nf*16 + lrow] = a2[r];
            }
        }
        __syncthreads();   // C2 visible; H2 reads done

        {   // layer-2 gates: one unit per thread (b2 = tid>>5 in 0..7)
            const int b2 = tid >> 5;
            const float cir = C2ih[b2*100 + j2t], ciz = C2ih[b2*100 + 32 + j2t], cin = C2ih[b2*100 + 64 + j2t];
            const float chr = C2hh[b2*100 + j2t], chz = C2hh[b2*100 + 32 + j2t], chn = C2hh[b2*100 + 64 + j2t];
            const float rg = sigf(cir + bi2r + chr + bh2r);
            const float zg = sigf(ciz + bi2z + chz + bh2z);
            const float ng = tanhf2(cin + bi2n + rg*(chn + bh2n));
            h2r = (1.f - zg)*ng + zg*h2r;
            const unsigned short hb = f2bf(h2r);
            H2hi[b2*40 + j2t] = hb;
            H2lo[b2*40 + j2t] = f2bf(h2r - bf2f(hb));
        }
        __syncthreads();   // H2(t) visible; C2 reads done before next overwrite

        #pragma unroll
        for (int kf = 0; kf < 2; ++kf)
            #pragma unroll
            for (int h = 0; h < 2; ++h)
                xc[kf][h] = xn[kf][h];
    }

    // head: fc = relu(h2_last @ Wfc^T + bfc); out = fc @ Wout^T + bout
    {
        const int b2 = tid >> 5;
        C2ih[b2*32 + j2t] = h2r;
    }
    __syncthreads();
    if (tid < 128){
        const int b = tid >> 4, f = tid & 15;
        float s = bfc[f];
        #pragma unroll
        for (int k = 0; k < 32; ++k) s += C2ih[b*32 + k] * Wfc[f*32 + k];
        s = fmaxf(s, 0.f);
        C2hh[b*16 + f] = s;
    }
    __syncthreads();
    if (tid < 8){
        float o = bout[0];
        #pragma unroll
        for (int f = 0; f < 16; ++f) o += C2hh[tid*16 + f] * Wout[f];
        out[blockIdx.x*8 + tid] = o;
    }
}

extern "C" void kernel_launch(void* const* d_in, const int* in_sizes, int n_in,
                              void* d_out, int out_size, void* d_ws, size_t ws_size,
                              hipStream_t stream) {
    const float* x    = (const float*)d_in[0];
    const float* Wih1 = (const float*)d_in[1];
    const float* Whh1 = (const float*)d_in[2];
    const float* bih1 = (const float*)d_in[3];
    const float* bhh1 = (const float*)d_in[4];
    const float* Wih2 = (const float*)d_in[5];
    const float* Whh2 = (const float*)d_in[6];
    const float* bih2 = (const float*)d_in[7];
    const float* bhh2 = (const float*)d_in[8];
    const float* Wfc  = (const float*)d_in[9];
    const float* bfc  = (const float*)d_in[10];
    const float* Wout = (const float*)d_in[11];
    const float* bout = (const float*)d_in[12];

    gru_fused<<<256, 256, 0, stream>>>(x, Wih1, Whh1, bih1, bhh1,
                                       Wih2, Whh2, bih2, bhh2,
                                       Wfc, bfc, Wout, bout, (float*)d_out);
}

// Round 3
// 531.247 us; speedup vs baseline: 1.2585x; 1.2585x over previous
//
#include <hip/hip_runtime.h>
#include <hip/hip_bf16.h>

#define T_SEQ 512

typedef __attribute__((ext_vector_type(8))) short frag_ab;
typedef __attribute__((ext_vector_type(4))) float frag_cd;

static __device__ __forceinline__ unsigned short f2bf(float f){
    union { float f; unsigned u; } v; v.f = f;
    unsigned r = v.u + 0x7fffu + ((v.u >> 16) & 1u);
    return (unsigned short)(r >> 16);
}
static __device__ __forceinline__ float bf2f(unsigned short h){
    union { unsigned u; float f; } v; v.u = ((unsigned)h) << 16;
    return v.f;
}
// sig(v) = 1/(1+2^(-v*log2e));  v->+inf -> 1; v->-inf -> rcp(inf)=0
static __device__ __forceinline__ float sigf(float v){
    return __builtin_amdgcn_rcpf(1.0f + __builtin_amdgcn_exp2f(-1.4426950408889634f * v));
}
static __device__ __forceinline__ float tanhf2(float v){
    return 2.0f * __builtin_amdgcn_rcpf(1.0f + __builtin_amdgcn_exp2f(-2.8853900817779268f * v)) - 1.0f;
}
static __device__ __forceinline__ frag_ab loadBfrag(const float* __restrict__ W, int ldk, int jcol, int k0){
    const float* p = W + jcol * ldk + k0;
    frag_ab r;
    #pragma unroll
    for (int i = 0; i < 8; ++i) r[i] = (short)f2bf(p[i]);
    return r;
}

#define MFMA(a,b,c) __builtin_amdgcn_mfma_f32_16x16x32_bf16((a),(b),(c),0,0,0)

// 8 waves: waves 0-3 ("P") = layer-1 GRU for step t; waves 4-7 ("C") = layer-2
// GRU for step t-1, via a depth-2 LDS ring of h1. 2 barriers/step.
__global__ __launch_bounds__(512, 2)
void gru_fused2(const float* __restrict__ x,
                const float* __restrict__ Wih1, const float* __restrict__ Whh1,
                const float* __restrict__ bih1, const float* __restrict__ bhh1,
                const float* __restrict__ Wih2, const float* __restrict__ Whh2,
                const float* __restrict__ bih2, const float* __restrict__ bhh2,
                const float* __restrict__ Wfc,  const float* __restrict__ bfc,
                const float* __restrict__ Wout, const float* __restrict__ bout,
                float* __restrict__ out)
{
    __shared__ __align__(16) unsigned short RGhi[2][8*72], RGlo[2][8*72]; // h1 ring
    __shared__ __align__(16) unsigned short XHI[2][8*72],  XLO[2][8*72];  // x staging
    __shared__ __align__(16) unsigned short H2hi[8*40],    H2lo[8*40];
    __shared__ __align__(16) float C2ih[16*100], C2hh[16*100];

    const int tid  = threadIdx.x;
    const int wv   = tid >> 6;         // 0..7
    const int lane = tid & 63;
    const int lrow = lane & 15;
    const int lq   = lane >> 4;
    const int r8   = lrow & 7;
    const bool isP = (wv < 4);
    const int cw   = wv - 4;           // C-wave index 0..3 (valid when !isP)

    for (int i = tid; i < 8*72; i += 512){
        RGhi[0][i]=0; RGhi[1][i]=0; RGlo[0][i]=0; RGlo[1][i]=0;
        XHI[1][i]=0;  XLO[1][i]=0;
    }
    for (int i = tid; i < 8*40; i += 512){ H2hi[i]=0; H2lo[i]=0; }

    // stage x(0): 512 threads x 1 element
    {
        const int b = tid >> 6, k = tid & 63;
        const float f = x[((size_t)(blockIdx.x*8 + b) * T_SEQ) * 64 + k];
        const unsigned short hb = f2bf(f);
        XHI[0][b*72 + k] = hb;
        XLO[0][b*72 + k] = f2bf(f - bf2f(hb));
    }

    // role-shared register files (overlap P/C lifetimes to cap VGPR)
    frag_ab WB[6][2];   // P: [0..2]=Wih1 gates, [3..5]=Whh1 gates ; C(cw<2): [0..2]=Wih2 ; C(cw>=2): [nf][0]=Whh2
    frag_cd BB[6];      // P: [0..2]=bih1, [3..5]=bhh1 splat ; C: [0..2]=bih2|bhh2 splat
    frag_ab FR[4][2];   // P: [0]=xhi,[1]=xlo,[2]=h1hi,[3]=h1lo ; C: [0]=nhi,[1]=nlo

    if (isP){
        const int j1 = wv*16 + lrow;
        #pragma unroll
        for (int g = 0; g < 3; ++g){
            #pragma unroll
            for (int kf = 0; kf < 2; ++kf){
                WB[g][kf]   = loadBfrag(Wih1, 64, g*64 + j1, kf*32 + 8*lq);
                WB[3+g][kf] = loadBfrag(Whh1, 64, g*64 + j1, kf*32 + 8*lq);
            }
            const float bi = bih1[g*64 + j1], bh = bhh1[g*64 + j1];
            BB[g]   = frag_cd{bi,bi,bi,bi};
            BB[3+g] = frag_cd{bh,bh,bh,bh};
        }
    } else if (cw < 2){
        #pragma unroll
        for (int nf = 0; nf < 3; ++nf){
            #pragma unroll
            for (int kf = 0; kf < 2; ++kf)
                WB[nf][kf] = loadBfrag(Wih2, 64, cw*48 + nf*16 + lrow, kf*32 + 8*lq);
            const float b2v = bih2[cw*48 + nf*16 + lrow];
            BB[nf] = frag_cd{b2v,b2v,b2v,b2v};
        }
    } else {
        #pragma unroll
        for (int nf = 0; nf < 3; ++nf){
            WB[nf][0] = loadBfrag(Whh2, 32, (cw-2)*48 + nf*16 + lrow, 8*lq);
            const float b2v = bhh2[(cw-2)*48 + nf*16 + lrow];
            BB[nf] = frag_cd{b2v,b2v,b2v,b2v};
        }
    }
    __syncthreads();

    // P initial fragment prefetch: x(0) and h1(-1)=0 (ring slot 1)
    if (isP){
        #pragma unroll
        for (int kf = 0; kf < 2; ++kf){
            const int o = r8*72 + kf*32 + 8*lq;
            FR[0][kf] = *(const frag_ab*)(XHI[0] + o);
            FR[1][kf] = *(const frag_ab*)(XLO[0] + o);
            FR[2][kf] = *(const frag_ab*)(RGhi[1] + o);
            FR[3][kf] = *(const frag_ab*)(RGlo[1] + o);
        }
    }

    const float* xbase = x + (size_t)(blockIdx.x*8) * T_SEQ * 64;
    const int sb = tid >> 5, skp = (tid & 31) * 2;     // P x-staging map (tid<256)

    float hp[4] = {0.f,0.f,0.f,0.f};   // P: h1 state, rows lq*4+r (dup &7), col wv*16+lrow
    float h2r = 0.f;                   // C: h2 state, unit (b2=(tid&255)>>5, j2=(tid&255)&31)

    for (int t = 0; t <= T_SEQ; ++t){
        // ---------------- phase 1 ----------------
        if (isP){
            if (t < T_SEQ){
                const int t1 = (t+1 < T_SEQ) ? t+1 : T_SEQ-1;
                const float* xp = xbase + (size_t)sb*T_SEQ*64 + (size_t)t1*64 + skp;
                const float xf0 = xp[0], xf1 = xp[1];   // issue early; used at end of phase

                frag_cd aih[3], ahh[3];
                #pragma unroll
                for (int g = 0; g < 3; ++g){ aih[g] = BB[g]; ahh[g] = BB[3+g]; }
                #pragma unroll
                for (int g = 0; g < 3; ++g){
                    #pragma unroll
                    for (int kf = 0; kf < 2; ++kf){
                        aih[g] = MFMA(FR[0][kf], WB[g][kf],   aih[g]);
                        aih[g] = MFMA(FR[1][kf], WB[g][kf],   aih[g]);
                        ahh[g] = MFMA(FR[2][kf], WB[3+g][kf], ahh[g]);
                        ahh[g] = MFMA(FR[3][kf], WB[3+g][kf], ahh[g]);
                    }
                }
                unsigned short* rh = RGhi[t&1];
                unsigned short* rl = RGlo[t&1];
                const int col = wv*16 + lrow;
                #pragma unroll
                for (int r = 0; r < 4; ++r){
                    const float rg = sigf(aih[0][r] + ahh[0][r]);
                    const float zg = sigf(aih[1][r] + ahh[1][r]);
                    const float ng = tanhf2(aih[2][r] + rg*ahh[2][r]);
                    const float hnew = ng + zg*(hp[r] - ng);
                    hp[r] = hnew;
                    const int row = (lq&1)*4 + r;      // rows 8..15 dup -> benign same-value race
                    const unsigned short hb = f2bf(hnew);
                    rh[row*72 + col] = hb;
                    rl[row*72 + col] = f2bf(hnew - bf2f(hb));
                }
                {   // stage x(t+1), unique 2 elems/thread
                    const unsigned short hb0 = f2bf(xf0), hb1 = f2bf(xf1);
                    const unsigned short lb0 = f2bf(xf0 - bf2f(hb0)), lb1 = f2bf(xf1 - bf2f(hb1));
                    unsigned short* xhp = XHI[(t+1)&1];
                    unsigned short* xlp = XLO[(t+1)&1];
                    *(unsigned*)(xhp + sb*72 + skp) = (unsigned)hb0 | ((unsigned)hb1 << 16);
                    *(unsigned*)(xlp + sb*72 + skp) = (unsigned)lb0 | ((unsigned)lb1 << 16);
                }
            }
        } else if (t >= 1){
            if (cw < 2){        // ih2 = h1(t-1) @ Wih2^T   (h1 frags prefetched)
                frag_cd a2[3];
                #pragma unroll
                for (int nf = 0; nf < 3; ++nf) a2[nf] = BB[nf];
                #pragma unroll
                for (int nf = 0; nf < 3; ++nf){
                    #pragma unroll
                    for (int kf = 0; kf < 2; ++kf){
                        a2[nf] = MFMA(FR[0][kf], WB[nf][kf], a2[nf]);
                        a2[nf] = MFMA(FR[1][kf], WB[nf][kf], a2[nf]);
                    }
                }
                #pragma unroll
                for (int nf = 0; nf < 3; ++nf)
                    #pragma unroll
                    for (int r = 0; r < 4; ++r)
                        C2ih[(lq*4+r)*100 + cw*48 + nf*16 + lrow] = a2[nf][r];
            } else {            // hh2 = h2(t-2) @ Whh2^T (K=32)
                const frag_ab g2h = *(const frag_ab*)(H2hi + r8*40 + 8*lq);
                const frag_ab g2l = *(const frag_ab*)(H2lo + r8*40 + 8*lq);
                #pragma unroll
                for (int nf = 0; nf < 3; ++nf){
                    frag_cd a2 = BB[nf];
                    a2 = MFMA(g2h, WB[nf][0], a2);
                    a2 = MFMA(g2l, WB[nf][0], a2);
                    #pragma unroll
                    for (int r = 0; r < 4; ++r)
                        C2hh[(lq*4+r)*100 + (cw-2)*48 + nf*16 + lrow] = a2[r];
                }
            }
        }
        __syncthreads();   // barA: h1(t) + x(t+1) + C2 visible
        // ---------------- phase 2 ----------------
        if (!isP){
            if (t >= 1){   // layer-2 gates for step t-1
                const int t2 = tid & 255;
                const int b2 = t2 >> 5, j2 = t2 & 31;
                const float rg = sigf(C2ih[b2*100 + j2]      + C2hh[b2*100 + j2]);
                const float zg = sigf(C2ih[b2*100 + 32 + j2] + C2hh[b2*100 + 32 + j2]);
                const float ng = tanhf2(C2ih[b2*100 + 64 + j2] + rg*C2hh[b2*100 + 64 + j2]);
                h2r = ng + zg*(h2r - ng);
                const unsigned short hb = f2bf(h2r);
                H2hi[b2*40 + j2] = hb;
                H2lo[b2*40 + j2] = f2bf(h2r - bf2f(hb));
            }
            if (t < T_SEQ && cw < 2){   // prefetch h1(t) ring frags for next step
                #pragma unroll
                for (int kf = 0; kf < 2; ++kf){
                    const int o = r8*72 + kf*32 + 8*lq;
                    FR[0][kf] = *(const frag_ab*)(RGhi[t&1] + o);
                    FR[1][kf] = *(const frag_ab*)(RGlo[t&1] + o);
                }
            }
        } else if (t+1 < T_SEQ){        // P prefetch x(t+1) + h1(t) frags
            #pragma unroll
            for (int kf = 0; kf < 2; ++kf){
                const int o = r8*72 + kf*32 + 8*lq;
                FR[0][kf] = *(const frag_ab*)(XHI[(t+1)&1] + o);
                FR[1][kf] = *(const frag_ab*)(XLO[(t+1)&1] + o);
                FR[2][kf] = *(const frag_ab*)(RGhi[t&1] + o);
                FR[3][kf] = *(const frag_ab*)(RGlo[t&1] + o);
            }
        }
        __syncthreads();   // barB: h2(t-1) visible; ring slot reads drained
    }

    // head: fc = relu(h2_last @ Wfc^T + bfc); out = fc @ Wout^T + bout
    if (!isP){
        const int t2 = tid & 255;
        C2ih[(t2>>5)*32 + (t2&31)] = h2r;
    }
    __syncthreads();
    if (tid < 128){
        const int b = tid >> 4, f = tid & 15;
        float s = bfc[f];
        #pragma unroll
        for (int k = 0; k < 32; ++k) s += C2ih[b*32 + k] * Wfc[f*32 + k];
        C2hh[b*16 + f] = fmaxf(s, 0.f);
    }
    __syncthreads();
    if (tid < 8){
        float o = bout[0];
        #pragma unroll
        for (int f = 0; f < 16; ++f) o += C2hh[tid*16 + f] * Wout[f];
        out[blockIdx.x*8 + tid] = o;
    }
}

extern "C" void kernel_launch(void* const* d_in, const int* in_sizes, int n_in,
                              void* d_out, int out_size, void* d_ws, size_t ws_size,
                              hipStream_t stream) {
    const float* x    = (const float*)d_in[0];
    const float* Wih1 = (const float*)d_in[1];
    const float* Whh1 = (const float*)d_in[2];
    const float* bih1 = (const float*)d_in[3];
    const float* bhh1 = (const float*)d_in[4];
    const float* Wih2 = (const float*)d_in[5];
    const float* Whh2 = (const float*)d_in[6];
    const float* bih2 = (const float*)d_in[7];
    const float* bhh2 = (const float*)d_in[8];
    const float* Wfc  = (const float*)d_in[9];
    const float* bfc  = (const float*)d_in[10];
    const float* Wout = (const float*)d_in[11];
    const float* bout = (const float*)d_in[12];

    gru_fused2<<<256, 512, 0, stream>>>(x, Wih1, Whh1, bih1, bhh1,
                                        Wih2, Whh2, bih2, bhh2,
                                        Wfc, bfc, Wout, bout, (float*)d_out);
}

// Round 4
// 497.705 us; speedup vs baseline: 1.3433x; 1.0674x over previous
//
#include <hip/hip_runtime.h>
#include <hip/hip_bf16.h>

#define T_SEQ 512

typedef __attribute__((ext_vector_type(8))) short frag_ab;
typedef __attribute__((ext_vector_type(4))) float frag_cd;

static __device__ __forceinline__ unsigned short f2bf_rnd(float f){
    union { float f; unsigned u; } v; v.f = f;
    unsigned r = v.u + 0x7fffu + ((v.u >> 16) & 1u);
    return (unsigned short)(r >> 16);
}
static __device__ __forceinline__ float bf2f(unsigned short h){
    union { unsigned u; float f; } v; v.u = ((unsigned)h) << 16;
    return v.f;
}
// truncation hi/lo split: hi = trunc-bf16(f), lo = trunc-bf16(f - hi). ~5 VALU.
static __device__ __forceinline__ void tsplit(float f, unsigned short &hi, unsigned short &lo){
    union { float f; unsigned u; } v; v.f = f;
    const unsigned uh = v.u & 0xFFFF0000u;
    hi = (unsigned short)(uh >> 16);
    union { unsigned u; float f; } w; w.u = uh;
    union { float f; unsigned u; } r; r.f = f - w.f;
    lo = (unsigned short)(r.u >> 16);
}
static __device__ __forceinline__ float sigf(float v){
    return __builtin_amdgcn_rcpf(1.0f + __builtin_amdgcn_exp2f(-1.4426950408889634f * v));
}
static __device__ __forceinline__ float tanhf2(float v){
    return 2.0f * __builtin_amdgcn_rcpf(1.0f + __builtin_amdgcn_exp2f(-2.8853900817779268f * v)) - 1.0f;
}
static __device__ __forceinline__ frag_ab loadBfrag(const float* __restrict__ W, int ldk, int jcol, int k0){
    const float* p = W + jcol * ldk + k0;
    frag_ab r;
    #pragma unroll
    for (int i = 0; i < 8; ++i) r[i] = (short)f2bf_rnd(p[i]);
    return r;
}

#define MFMA(a,b,c) __builtin_amdgcn_mfma_f32_16x16x32_bf16((a),(b),(c),0,0,0)

// 8 waves, ONE barrier per timestep.
// Waves 0-3 ("P"): layer-1 GRU for step t (each owns 16 h1-columns).
// Waves 4-7 ("C"): each redundantly computes ALL of layer-2 for step t-1
//   fully in-register (ih2+hh2 chained into the same accumulators, gates read
//   accumulators directly); gate rows split by wave index cw (static unroll).
// LDS rings (all depth-2, writer-slot != reader-slot within a phase):
//   X[s]  = x(s) hi/lo      staged by C in phase s-1, read by P in phase s
//   RG[s] = h1(s) hi/lo     written by P in phase s, read by P+C in phase s+1
//   H2[s] = h2(s) hi/lo     written by C in phase s+1, read by C in phase s+2
__global__ __launch_bounds__(512, 2)
void gru_fused3(const float* __restrict__ x,
                const float* __restrict__ Wih1, const float* __restrict__ Whh1,
                const float* __restrict__ bih1, const float* __restrict__ bhh1,
                const float* __restrict__ Wih2, const float* __restrict__ Whh2,
                const float* __restrict__ bih2, const float* __restrict__ bhh2,
                const float* __restrict__ Wfc,  const float* __restrict__ bfc,
                const float* __restrict__ Wout, const float* __restrict__ bout,
                float* __restrict__ out)
{
    __shared__ __align__(16) unsigned short RGhi[2][576], RGlo[2][576];  // [slot][row*72+col]
    __shared__ __align__(16) unsigned short XHI[2][576],  XLO[2][576];
    __shared__ __align__(16) unsigned short H2HI[2][320], H2LO[2][320];  // [slot][row*40+col]
    __shared__ float HFIN[256];
    __shared__ float FCS[128];

    const int tid  = threadIdx.x;
    const int wv   = tid >> 6;
    const int lane = tid & 63;
    const int lrow = lane & 15;
    const int lq   = lane >> 4;
    const int r8   = lrow & 7;
    const bool isP = (wv < 4);
    const int cw   = wv - 4;

    // zero the "-1" state slots
    for (int i = tid; i < 576; i += 512){ RGhi[1][i] = 0; RGlo[1][i] = 0; }
    for (int i = tid; i < 320; i += 512){ H2HI[1][i] = 0; H2LO[1][i] = 0; }

    // stage x(0) into X[0]: 512 threads x 1 element
    {
        const int b = tid >> 6, k = tid & 63;
        unsigned short hb, lb;
        tsplit(x[((size_t)(blockIdx.x*8 + b) * T_SEQ) * 64 + k], hb, lb);
        XHI[0][b*72 + k] = hb; XLO[0][b*72 + k] = lb;
    }

    // role-unioned register files
    frag_ab WU[18];     // P: [g*4 + {ih kf0, ih kf1, hh kf0, hh kf1}], g=0..2 (12 used)
                        // C: [0..3]=R-ih[b][kf], [4..7]=Z-ih, [8..11]=N-ih,
                        //    [12..13]=R-hh[b], [14..15]=Z-hh, [16..17]=N-hh
    frag_cd AU[8];      // P: 0=R,1=Z,2=N-ih,3=N-hh ; C: [0+b]=R,[2+b]=Z,[4+b]=N-ih,[6+b]=N-hh
    frag_ab FU[8];      // P: 0,1=xhi; 2,3=xlo; 4,5=h1hi; 6,7=h1lo
                        // C: 0,1=h1hi; 2,3=h1lo; 4=h2hi; 5=h2lo
    float   BU[8];      // biases (combined r/z, separate n-ih/n-hh)
    float   HS[2] = {0.f, 0.f};   // recurrent state (2 units per lane)

    if (isP){
        const int j = wv*16 + lrow;
        #pragma unroll
        for (int g = 0; g < 3; ++g){
            #pragma unroll
            for (int kf = 0; kf < 2; ++kf){
                WU[g*4 + kf]     = loadBfrag(Wih1, 64, g*64 + j, kf*32 + 8*lq);
                WU[g*4 + 2 + kf] = loadBfrag(Whh1, 64, g*64 + j, kf*32 + 8*lq);
            }
        }
        BU[0] = bih1[j]       + bhh1[j];
        BU[1] = bih1[64 + j]  + bhh1[64 + j];
        BU[2] = bih1[128 + j];
        BU[3] = bhh1[128 + j];
    } else {
        #pragma unroll
        for (int b = 0; b < 2; ++b){
            const int c = b*16 + lrow;
            #pragma unroll
            for (int kf = 0; kf < 2; ++kf){
                WU[0 + b*2 + kf] = loadBfrag(Wih2, 64, c,      kf*32 + 8*lq);
                WU[4 + b*2 + kf] = loadBfrag(Wih2, 64, 32 + c, kf*32 + 8*lq);
                WU[8 + b*2 + kf] = loadBfrag(Wih2, 64, 64 + c, kf*32 + 8*lq);
            }
            WU[12 + b] = loadBfrag(Whh2, 32, c,      8*lq);
            WU[14 + b] = loadBfrag(Whh2, 32, 32 + c, 8*lq);
            WU[16 + b] = loadBfrag(Whh2, 32, 64 + c, 8*lq);
            BU[0 + b] = bih2[c]      + bhh2[c];
            BU[2 + b] = bih2[32 + c] + bhh2[32 + c];
            BU[4 + b] = bih2[64 + c];
            BU[6 + b] = bhh2[64 + c];
        }
    }
    __syncthreads();

    const float* xbase = x + (size_t)(blockIdx.x*8) * T_SEQ * 64;

    for (int t = 0; t <= T_SEQ; ++t){
        const int sCur = t & 1, sPrev = (t + 1) & 1;
        if (isP){
            if (t < T_SEQ){
                #pragma unroll
                for (int kf = 0; kf < 2; ++kf){
                    const int o = r8*72 + kf*32 + 8*lq;
                    FU[0+kf] = *(const frag_ab*)(XHI[sCur]  + o);
                    FU[2+kf] = *(const frag_ab*)(XLO[sCur]  + o);
                    FU[4+kf] = *(const frag_ab*)(RGhi[sPrev] + o);
                    FU[6+kf] = *(const frag_ab*)(RGlo[sPrev] + o);
                }
                #pragma unroll
                for (int a = 0; a < 4; ++a) AU[a] = frag_cd{0.f,0.f,0.f,0.f};
                #pragma unroll
                for (int kf = 0; kf < 2; ++kf){
                    AU[0] = MFMA(FU[0+kf], WU[0+kf],  AU[0]);
                    AU[0] = MFMA(FU[2+kf], WU[0+kf],  AU[0]);
                    AU[0] = MFMA(FU[4+kf], WU[2+kf],  AU[0]);
                    AU[0] = MFMA(FU[6+kf], WU[2+kf],  AU[0]);
                    AU[1] = MFMA(FU[0+kf], WU[4+kf],  AU[1]);
                    AU[1] = MFMA(FU[2+kf], WU[4+kf],  AU[1]);
                    AU[1] = MFMA(FU[4+kf], WU[6+kf],  AU[1]);
                    AU[1] = MFMA(FU[6+kf], WU[6+kf],  AU[1]);
                    AU[2] = MFMA(FU[0+kf], WU[8+kf],  AU[2]);
                    AU[2] = MFMA(FU[2+kf], WU[8+kf],  AU[2]);
                    AU[3] = MFMA(FU[4+kf], WU[10+kf], AU[3]);
                    AU[3] = MFMA(FU[6+kf], WU[10+kf], AU[3]);
                }
                // gate-row dedup: lanes<32 take acc rows {0,1}, lanes>=32 rows {2,3}
                const bool selLo = (lane < 32);
                const float vR0 = selLo ? AU[0][0] : AU[0][2], vR1 = selLo ? AU[0][1] : AU[0][3];
                const float vZ0 = selLo ? AU[1][0] : AU[1][2], vZ1 = selLo ? AU[1][1] : AU[1][3];
                const float vI0 = selLo ? AU[2][0] : AU[2][2], vI1 = selLo ? AU[2][1] : AU[2][3];
                const float vH0 = selLo ? AU[3][0] : AU[3][2], vH1 = selLo ? AU[3][1] : AU[3][3];

                const float rg0 = sigf(vR0 + BU[0]);
                const float zg0 = sigf(vZ0 + BU[1]);
                const float ng0 = tanhf2(vI0 + BU[2] + rg0*(vH0 + BU[3]));
                const float h0  = ng0 + zg0*(HS[0] - ng0); HS[0] = h0;

                const float rg1 = sigf(vR1 + BU[0]);
                const float zg1 = sigf(vZ1 + BU[1]);
                const float ng1 = tanhf2(vI1 + BU[2] + rg1*(vH1 + BU[3]));
                const float h1v = ng1 + zg1*(HS[1] - ng1); HS[1] = h1v;

                // rows: lq=0->{0,1}, lq=1->{4,5}, lq=2->{2,3}, lq=3->{6,7}; unique writers
                const int rowb = (lq & 1)*4 + (lq >> 1)*2;
                const int col  = wv*16 + lrow;
                unsigned short hb, lb;
                tsplit(h0, hb, lb);
                RGhi[sCur][rowb*72 + col] = hb;       RGlo[sCur][rowb*72 + col] = lb;
                tsplit(h1v, hb, lb);
                RGhi[sCur][(rowb+1)*72 + col] = hb;   RGlo[sCur][(rowb+1)*72 + col] = lb;
            }
        } else {
            float2 xf = {0.f, 0.f};
            int xr = 0, xk = 0;
            if (t < T_SEQ){   // issue x(t+1) load early; consumed at phase end
                const int t1 = (t+1 < T_SEQ) ? (t+1) : (T_SEQ-1);
                const int v = cw*128 + lane*2;
                xr = v >> 6; xk = v & 63;
                xf = *(const float2*)(xbase + ((size_t)xr * T_SEQ + t1)*64 + xk);
            }
            if (t >= 1){      // layer-2 step s = t-1, fully in-register
                #pragma unroll
                for (int kf = 0; kf < 2; ++kf){
                    const int o = r8*72 + kf*32 + 8*lq;
                    FU[0+kf] = *(const frag_ab*)(RGhi[sPrev] + o);
                    FU[2+kf] = *(const frag_ab*)(RGlo[sPrev] + o);
                }
                FU[4] = *(const frag_ab*)(H2HI[sCur] + r8*40 + 8*lq);
                FU[5] = *(const frag_ab*)(H2LO[sCur] + r8*40 + 8*lq);
                #pragma unroll
                for (int a = 0; a < 8; ++a) AU[a] = frag_cd{0.f,0.f,0.f,0.f};
                #pragma unroll
                for (int b = 0; b < 2; ++b){
                    #pragma unroll
                    for (int kf = 0; kf < 2; ++kf){
                        AU[0+b] = MFMA(FU[0+kf], WU[0+b*2+kf], AU[0+b]);
                        AU[0+b] = MFMA(FU[2+kf], WU[0+b*2+kf], AU[0+b]);
                        AU[2+b] = MFMA(FU[0+kf], WU[4+b*2+kf], AU[2+b]);
                        AU[2+b] = MFMA(FU[2+kf], WU[4+b*2+kf], AU[2+b]);
                        AU[4+b] = MFMA(FU[0+kf], WU[8+b*2+kf], AU[4+b]);
                        AU[4+b] = MFMA(FU[2+kf], WU[8+b*2+kf], AU[4+b]);
                    }
                    AU[0+b] = MFMA(FU[4], WU[12+b], AU[0+b]);
                    AU[0+b] = MFMA(FU[5], WU[12+b], AU[0+b]);
                    AU[2+b] = MFMA(FU[4], WU[14+b], AU[2+b]);
                    AU[2+b] = MFMA(FU[5], WU[14+b], AU[2+b]);
                    AU[6+b] = MFMA(FU[4], WU[16+b], AU[6+b]);
                    AU[6+b] = MFMA(FU[5], WU[16+b], AU[6+b]);
                }
                const int sW = (t + 1) & 1;   // == (t-1)&1: slot for h2(t-1)
                #pragma unroll
                for (int K = 0; K < 4; ++K) if (cw == K){   // wave-uniform, static K
                    #pragma unroll
                    for (int b = 0; b < 2; ++b){
                        const float rv  = sigf(AU[0+b][K] + BU[0+b]);
                        const float zv  = sigf(AU[2+b][K] + BU[2+b]);
                        const float nv  = tanhf2(AU[4+b][K] + BU[4+b] + rv*(AU[6+b][K] + BU[6+b]));
                        const float hn  = nv + zv*(HS[b] - nv);
                        HS[b] = hn;
                        if (lq < 2){   // rows cw, cw+4 only (dup lanes masked)
                            unsigned short hb, lb; tsplit(hn, hb, lb);
                            H2HI[sW][(lq*4+K)*40 + b*16 + lrow] = hb;
                            H2LO[sW][(lq*4+K)*40 + b*16 + lrow] = lb;
                        }
                    }
                }
            }
            if (t < T_SEQ){   // stage x(t+1): trunc-split, packed b32 writes
                unsigned short h0,l0,h1_,l1_;
                tsplit(xf.x, h0, l0); tsplit(xf.y, h1_, l1_);
                *(unsigned*)(&XHI[sPrev][xr*72 + xk]) = (unsigned)h0 | ((unsigned)h1_ << 16);
                *(unsigned*)(&XLO[sPrev][xr*72 + xk]) = (unsigned)l0 | ((unsigned)l1_ << 16);
            }
        }
        __syncthreads();
    }

    // head: h2(T-1) lives in H2 slot (T_SEQ-1)&1 as hi/lo
    if (tid < 256){
        const int r = tid >> 5, c = tid & 31;
        const int s = (T_SEQ - 1) & 1;
        HFIN[r*32 + c] = bf2f(H2HI[s][r*40 + c]) + bf2f(H2LO[s][r*40 + c]);
    }
    __syncthreads();
    if (tid < 128){
        const int b = tid >> 4, f = tid & 15;
        float s = bfc[f];
        #pragma unroll
        for (int k = 0; k < 32; ++k) s += HFIN[b*32 + k] * Wfc[f*32 + k];
        FCS[b*16 + f] = fmaxf(s, 0.f);
    }
    __syncthreads();
    if (tid < 8){
        float o = bout[0];
        #pragma unroll
        for (int f = 0; f < 16; ++f) o += FCS[tid*16 + f] * Wout[f];
        out[blockIdx.x*8 + tid] = o;
    }
}

extern "C" void kernel_launch(void* const* d_in, const int* in_sizes, int n_in,
                              void* d_out, int out_size, void* d_ws, size_t ws_size,
                              hipStream_t stream) {
    const float* x    = (const float*)d_in[0];
    const float* Wih1 = (const float*)d_in[1];
    const float* Whh1 = (const float*)d_in[2];
    const float* bih1 = (const float*)d_in[3];
    const float* bhh1 = (const float*)d_in[4];
    const float* Wih2 = (const float*)d_in[5];
    const float* Whh2 = (const float*)d_in[6];
    const float* bih2 = (const float*)d_in[7];
    const float* bhh2 = (const float*)d_in[8];
    const float* Wfc  = (const float*)d_in[9];
    const float* bfc  = (const float*)d_in[10];
    const float* Wout = (const float*)d_in[11];
    const float* bout = (const float*)d_in[12];

    gru_fused3<<<256, 512, 0, stream>>>(x, Wih1, Whh1, bih1, bhh1,
                                        Wih2, Whh2, bih2, bhh2,
                                        Wfc, bfc, Wout, bout, (float*)d_out);
}